// Round 16
// baseline (286.184 us; speedup 1.0000x reference)
//
#include <hip/hip_runtime.h>

typedef unsigned short u16;
typedef unsigned int   u32;
typedef unsigned long long u64;
typedef __attribute__((ext_vector_type(8))) u16  u16x8;
typedef __attribute__((ext_vector_type(4))) float f32x4;

#define N_PTS   131072
#define M_PTS   32768
#define BNCF    0.9999950000374997f

__device__ __forceinline__ float b2f(u16 u) {
    u32 x = ((u32)u) << 16;
    float f;
    __builtin_memcpy(&f, &x, 4);
    return f;
}
// cold-path bit-trick (RNE)
__device__ __forceinline__ u16 f2b(float f) {
    u32 x;
    __builtin_memcpy(&x, &f, 4);
    u32 r = x + 0x7fffu + ((x >> 16) & 1u);
    return (u16)(r >> 16);
}
// hot-path: single v_cvt_pk_bf16_f32 (RNE on finite values — identical to bit-trick)
__device__ __forceinline__ u16 f2b_hw(float f) {
    u32 r;
    asm("v_cvt_pk_bf16_f32 %0, %1, %1" : "=v"(r) : "v"(f));
    return (u16)r;
}
// packed: lo16 = bf16(a), hi16 = bf16(b) — one instruction for two converts
__device__ __forceinline__ u32 f2b2(float a, float b) {
    u32 r;
    asm("v_cvt_pk_bf16_f32 %0, %1, %2" : "=v"(r) : "v"(a), "v"(b));
    return r;
}
// silu without IEEE division: 5 ops (mul,exp,add,rcp,mul) vs ~13 with div sequence
__device__ __forceinline__ float silu_f(float x) {
    return x * __builtin_amdgcn_rcpf(1.0f + __expf(-x));
}

__device__ __forceinline__ f32x4 mfma_bf16(u16x8 a, u16x8 b, f32x4 c) {
    asm volatile("v_mfma_f32_16x16x32_bf16 %0, %1, %2, %0"
                 : "+v"(c) : "v"(a), "v"(b));
    return c;
}
// Single MAI->VALU wait-state guard, issued ONCE before each epilogue.
// NOTE (R14 lesson): inline-asm MFMA is invisible to the compiler's hazard
// logic — launch_bounds must NEVER force spills.
__device__ __forceinline__ void mai_guard() {
    asm volatile("s_nop 7\n\ts_nop 7\n\ts_nop 3");
}

// async global->LDS, 16B per lane. LDS dest = wave-uniform base + lane*16.
__device__ __forceinline__ void cp_glds16(const u16* g, u16* l) {
    typedef const __attribute__((address_space(1))) u32* gp1_t;
    typedef __attribute__((address_space(3))) u32* lp3_t;
    __builtin_amdgcn_global_load_lds((gp1_t)(unsigned long long)g,
                                     (lp3_t)(unsigned long long)l, 16, 0, 0);
}

// ---------------------------------------------------------------- all weight transposes in ONE dispatch
__global__ __launch_bounds__(256) void k_prep(const float* __restrict__ expw, u16* __restrict__ expwt,
                                              const float* __restrict__ pw1w, u16* __restrict__ pw1t,
                                              const float* __restrict__ pw2w, u16* __restrict__ pw2t,
                                              const float* __restrict__ prjw, u16* __restrict__ prjt,
                                              const float* __restrict__ lw1,  u16* __restrict__ lw1t,
                                              const float* __restrict__ lw2,  u16* __restrict__ lw2t,
                                              const float* __restrict__ sw1,  u16* __restrict__ sw1t,
                                              const float* __restrict__ sw2,  u16* __restrict__ sw2t,
                                              float* __restrict__ cent) {
    __shared__ u16 tile[64][66];
    int bid = blockIdx.x;
    if (bid < 160) {
        const float* W; u16* O; int K, Nn, tk, tn_;
        if (bid < 16)              { W = expw; O = expwt; K = 128; Nn = 512; tk = bid >> 3; tn_ = bid & 7; }
        else if ((bid -= 16) < 64) { W = pw1w; O = pw1t;  K = 512; Nn = 512; tk = bid >> 3; tn_ = bid & 7; }
        else if ((bid -= 64) < 64) { W = pw2w; O = pw2t;  K = 512; Nn = 512; tk = bid >> 3; tn_ = bid & 7; }
        else { bid -= 64;            W = prjw; O = prjt;  K = 512; Nn = 128; tk = bid >> 1; tn_ = bid & 1; }
        int k0 = tk * 64, n0 = tn_ * 64;
        int c = threadIdx.x & 63, r0 = threadIdx.x >> 6;
#pragma unroll
        for (int rr = 0; rr < 16; ++rr) {
            int row = r0 * 16 + rr;
            tile[row][c] = f2b(W[(long)(k0 + row) * Nn + n0 + c]);
        }
        __syncthreads();
#pragma unroll
        for (int rr = 0; rr < 16; ++rr) {
            int row = r0 * 16 + rr;
            O[(long)(n0 + row) * K + k0 + c] = tile[c][row];
        }
        return;
    }
    int idx = (bid - 160) * 256 + threadIdx.x;
    if (bid == 247 && threadIdx.x < 16) cent[threadIdx.x] = 0.0f;
    const float* W; u16* O; int K, ksh, Nn;
    if (idx < 4096)                  { W = lw1; O = lw1t; K = 39; ksh = 6; Nn = 64;  }
    else if ((idx -= 4096) < 8192)   { W = lw2; O = lw2t; K = 64; ksh = 6; Nn = 128; }
    else if ((idx -= 8192) < 8192)   { W = sw1; O = sw1t; K = 97; ksh = 7; Nn = 64;  }
    else if ((idx -= 8192) < 2048)   { W = sw2; O = sw2t; K = 64; ksh = 6; Nn = 32;  }
    else return;
    int n = idx >> ksh, k = idx & ((1 << ksh) - 1);
    O[idx] = (k < K) ? f2b(W[(long)k * Nn + n]) : (u16)0;
}

// ---------------------------------------------------------------- centers
__global__ __launch_bounds__(256) void k_centers(const float* __restrict__ pos,
                                                 const float* __restrict__ sfv,
                                                 const int* __restrict__ batch,
                                                 float* __restrict__ acc) {
    __shared__ float ls[16];
    int t = threadIdx.x, lane = t & 63, wave = t >> 6;
    int i = blockIdx.x * 256 + t;
    int b = batch[blockIdx.x * 256];                 // block-uniform
    float inv = 1.0f / sfv[b];
    float x = pos[i * 3 + 0] * inv;
    float y = pos[i * 3 + 1] * inv;
    float z = pos[i * 3 + 2] * inv;
#pragma unroll
    for (int m = 1; m < 64; m <<= 1) {
        x += __shfl_xor(x, m);
        y += __shfl_xor(y, m);
        z += __shfl_xor(z, m);
    }
    if (lane == 0) { ls[wave * 4 + 0] = x; ls[wave * 4 + 1] = y; ls[wave * 4 + 2] = z; }
    __syncthreads();
    if (t < 3) {
        float s = ls[t] + ls[4 + t] + ls[8 + t] + ls[12 + t];
        atomicAdd(&acc[b * 4 + t], s);
    }
    if (t == 3) atomicAdd(&acc[b * 4 + 3], 256.0f);
}

// ---------------------------------------------------------------- stem (MFMA)
// NEW: BARRIER-FREE. All phases are per-wave-row-owned (feature phase writes
// rows t>>1 = wave's own 32 rows; both MFMA stages read/write only those rows;
// same-wave DS ops are in-order). Both MFMA stages use OPERAND-SWAPPED mfma
// (D[n][m]: lane holds m=l16, n=j*16+quad*4+r) so epilogue writes are PACKED:
// stage-1 h-write 32 scalar u16 -> 8 ds_write_b64; stage-2 xout 16 scalar ->
// 4 global dwordx2. Same products, same layout in memory — only write width.
__global__ __launch_bounds__(256, 4) void k_stem(const float* __restrict__ pos,
                                              const float* __restrict__ refl,
                                              const float* __restrict__ sfv,
                                              const int* __restrict__ batch,
                                              const float* __restrict__ cacc,
                                              const float* __restrict__ g,
                                              const float* __restrict__ bb,
                                              const u16* __restrict__ w1t,   // [64][128] bf16 (zero pad k>=97)
                                              const float* __restrict__ b1,
                                              const u16* __restrict__ w2t,   // [32][64] bf16
                                              const float* __restrict__ b2,
                                              u16* __restrict__ xout) {
    __shared__ u16 xs[128][136];
    const float FLO[8] = {
        1.0f, 0.31622776601683794f, 0.1f, 0.031622776601683791f,
        0.01f, 0.0031622776601683794f, 0.001f, 0.00031622776601683794f};
    const float FHI[8] = {
        0.0001f, 3.1622776601683795e-05f, 1e-05f, 3.1622776601683796e-06f,
        1e-06f, 3.1622776601683797e-07f, 1e-07f, 3.1622776601683792e-08f};
    int t = threadIdx.x;
    int wave = t >> 6, lane = t & 63;
    int quad = lane >> 4, l16 = lane & 15;
    int mt0 = wave * 2;

    {
        int p = t >> 1, half = t & 1;
        int i = blockIdx.x * 128 + p;
        int b = batch[i];
        float s = 1.0f / sfv[b];
        float cnt = fmaxf(cacc[b * 4 + 3], 1.0f);
        float npv[3];
#pragma unroll
        for (int d = 0; d < 3; ++d)
            npv[d] = pos[i * 3 + d] * s - cacc[b * 4 + d] / cnt;

        float fq[8];
#pragma unroll
        for (int f = 0; f < 8; ++f) fq[f] = half ? FHI[f] : FLO[f];

        float sv[3][8], cv[3][8];
        float sum = 0.0f, sq = 0.0f;
#pragma unroll
        for (int d = 0; d < 3; ++d) {
#pragma unroll
            for (int f = 0; f < 8; ++f) {
                float a = npv[d] * fq[f];
                float s_, c_;
                __sincosf(a, &s_, &c_);
                sv[d][f] = s_;
                cv[d][f] = c_;
                sum += s_ + c_;
                sq += s_ * s_ + c_ * c_;
            }
        }
        float rf = refl[i];
        if (half == 0) { sum += rf; sq += rf * rf; }
        sum += __shfl_xor(sum, 1);
        sq  += __shfl_xor(sq, 1);

        float m = sum * (1.0f / 97.0f);
        float var = sq * (1.0f / 97.0f) - m * m;
        float rstd = rsqrtf(fmaxf(var, 0.0f) + 1e-5f);

#pragma unroll
        for (int d = 0; d < 3; ++d) {
            int c0 = d * 32 + half * 8;          // sin block
            {
                f32x4 g0  = *(const f32x4*)(g + c0);
                f32x4 g1  = *(const f32x4*)(g + c0 + 4);
                f32x4 bb0 = *(const f32x4*)(bb + c0);
                f32x4 bb1 = *(const f32x4*)(bb + c0 + 4);
                u16 tmp[8];
#pragma unroll
                for (int f = 0; f < 4; ++f) {
                    tmp[f]     = f2b_hw((sv[d][f]     - m) * rstd * g0[f] + bb0[f]);
                    tmp[4 + f] = f2b_hw((sv[d][4 + f] - m) * rstd * g1[f] + bb1[f]);
                }
                *(uint4*)(&xs[p][c0]) = *(uint4*)tmp;
            }
            int c1 = d * 32 + 16 + half * 8;     // cos block
            {
                f32x4 g0  = *(const f32x4*)(g + c1);
                f32x4 g1  = *(const f32x4*)(g + c1 + 4);
                f32x4 bb0 = *(const f32x4*)(bb + c1);
                f32x4 bb1 = *(const f32x4*)(bb + c1 + 4);
                u16 tmp[8];
#pragma unroll
                for (int f = 0; f < 4; ++f) {
                    tmp[f]     = f2b_hw((cv[d][f]     - m) * rstd * g0[f] + bb0[f]);
                    tmp[4 + f] = f2b_hw((cv[d][4 + f] - m) * rstd * g1[f] + bb1[f]);
                }
                *(uint4*)(&xs[p][c1]) = *(uint4*)tmp;
            }
        }
        if (half == 0) {
            float v = rf;
            u16 tmp[8];
            tmp[0] = f2b_hw((v - m) * rstd * g[96] + bb[96]);
#pragma unroll
            for (int f = 1; f < 8; ++f) tmp[f] = 0;
            *(uint4*)(&xs[p][96]) = *(uint4*)tmp;    // cols 96..103
        } else {
            uint4 z = {0, 0, 0, 0};
            *(uint4*)(&xs[p][104]) = z;              // cols 104..127
            *(uint4*)(&xs[p][112]) = z;
            *(uint4*)(&xs[p][120]) = z;
        }
    }
    // NO barrier: each wave's feature rows (t>>1 in [wave*32, wave*32+32)) are
    // exactly the rows its own MFMA stages read (same-wave DS in-order).

    {
        f32x4 acc[2][4];
#pragma unroll
        for (int i = 0; i < 2; ++i)
#pragma unroll
            for (int j = 0; j < 4; ++j) acc[i][j] = (f32x4){0.f, 0.f, 0.f, 0.f};
#pragma unroll
        for (int kk = 0; kk < 128; kk += 32) {
            u16x8 af[2], bfr[4];
#pragma unroll
            for (int i = 0; i < 2; ++i)
                af[i] = *(const u16x8*)(&xs[(mt0 + i) * 16 + l16][kk + quad * 8]);
#pragma unroll
            for (int j = 0; j < 4; ++j)
                bfr[j] = *(const u16x8*)(w1t + (j * 16 + l16) * 128 + kk + quad * 8);
#pragma unroll
            for (int i = 0; i < 2; ++i)
#pragma unroll
                for (int j = 0; j < 4; ++j)
                    acc[i][j] = mfma_bf16(bfr[j], af[i], acc[i][j]);   // SWAPPED: D[n][m]
        }
        mai_guard();
        // lane: m = (mt0+i)*16 + l16 (own row), n = j*16 + quad*4 + r (packed)
#pragma unroll
        for (int j = 0; j < 4; ++j) {
            f32x4 bv = *(const f32x4*)(b1 + j * 16 + quad * 4);
#pragma unroll
            for (int i = 0; i < 2; ++i) {
                f32x4 c = acc[i][j];
                int mrow = (mt0 + i) * 16 + l16;
                float v0 = silu_f(fmaf(BNCF, c[0], bv[0] * BNCF));
                float v1 = silu_f(fmaf(BNCF, c[1], bv[1] * BNCF));
                float v2 = silu_f(fmaf(BNCF, c[2], bv[2] * BNCF));
                float v3 = silu_f(fmaf(BNCF, c[3], bv[3] * BNCF));
                u32 p2[2] = { f2b2(v0, v1), f2b2(v2, v3) };
                *(u64*)(&xs[mrow][j * 16 + quad * 4]) = *(u64*)p2;
            }
        }
    }
    // NO barrier: stage-2 reads only this wave's own rows.

    {
        f32x4 acc[2][2];
#pragma unroll
        for (int i = 0; i < 2; ++i)
#pragma unroll
            for (int j = 0; j < 2; ++j) acc[i][j] = (f32x4){0.f, 0.f, 0.f, 0.f};
#pragma unroll
        for (int kk = 0; kk < 64; kk += 32) {
            u16x8 af[2], bfr[2];
#pragma unroll
            for (int i = 0; i < 2; ++i)
                af[i] = *(const u16x8*)(&xs[(mt0 + i) * 16 + l16][kk + quad * 8]);
#pragma unroll
            for (int j = 0; j < 2; ++j)
                bfr[j] = *(const u16x8*)(w2t + (j * 16 + l16) * 64 + kk + quad * 8);
#pragma unroll
            for (int i = 0; i < 2; ++i)
#pragma unroll
                for (int j = 0; j < 2; ++j)
                    acc[i][j] = mfma_bf16(bfr[j], af[i], acc[i][j]);   // SWAPPED: D[n][m]
        }
        mai_guard();
#pragma unroll
        for (int j = 0; j < 2; ++j) {
            f32x4 bv = *(const f32x4*)(b2 + j * 16 + quad * 4);
#pragma unroll
            for (int i = 0; i < 2; ++i) {
                f32x4 c = acc[i][j];
                int m = (mt0 + i) * 16 + l16;
                long ig = (long)blockIdx.x * 128 + m;
                float v0 = silu_f(fmaf(BNCF, c[0], bv[0] * BNCF));
                float v1 = silu_f(fmaf(BNCF, c[1], bv[1] * BNCF));
                float v2 = silu_f(fmaf(BNCF, c[2], bv[2] * BNCF));
                float v3 = silu_f(fmaf(BNCF, c[3], bv[3] * BNCF));
                u32 p2[2] = { f2b2(v0, v1), f2b2(v2, v3) };
                *(u64*)(xout + ig * 32 + j * 16 + quad * 4) = *(u64*)p2;
            }
        }
    }
}

// ---------------------------------------------------------------- edge MLP + segment max (MFMA)
// R13 single-barrier structure. NEW: stage-1 operand-swapped -> packed h-writes
// (8 ds_write_b64 + 16 cvt_pk vs 32 scalar u16 + 32 cvt). Stage-2 unchanged
// (its column-per-lane layout is what makes the 16-edge segment-max cheap).
__global__ __launch_bounds__(256, 4) void k_edge(const float* __restrict__ pos,
                                              const float* __restrict__ refl,
                                              const int* __restrict__ idxp,
                                              const int* __restrict__ colp,
                                              const u16* __restrict__ xfeat,
                                              const float* __restrict__ lkw,
                                              const float* __restrict__ lkb,
                                              const float* __restrict__ lng,
                                              const float* __restrict__ lnb,
                                              const u16* __restrict__ w1t,
                                              const float* __restrict__ b1,
                                              const u16* __restrict__ w2t,
                                              const float* __restrict__ b2,
                                              float* __restrict__ agg,
                                              u16* __restrict__ aggb) {
    __shared__ u16 msgA[128 * 32];   // msg cols 0..31 -> h cols 0..31
    __shared__ u16 msgB[128 * 32];   // msg cols 32..63 -> h cols 32..63
    __shared__ u16 ws1[64 * 64];     // w1, slot = gch ^ (row&7)
    __shared__ u16 ws2[128 * 64];    // w2, slot = gch ^ (row&7)
    int t = threadIdx.x;
    int r0 = blockIdx.x * 8;
    long e0 = (long)r0 * 16;
    int wave = t >> 6, lane = t & 63;
    int quad = lane >> 4, l16 = lane & 15;
    int mt0 = wave * 2;

    // stage-2 biases -> registers (stage-2 keeps n = j*16 + l16 layout)
    float b2A[8];
#pragma unroll
    for (int j = 0; j < 8; ++j) b2A[j] = b2[j * 16 + l16] * BNCF;

    if (t >= 128) {
        // waves 2-3: ALL DMA staging (w2, w1, xfeat gather)
        int gw = (t >> 6) - 2;           // 0/1
#pragma unroll
        for (int it = 0; it < 8; ++it) { // ws2: 1024 chunks
            int cb = it * 128 + gw * 64;
            int ch = cb + lane;
            int row = ch >> 3, sl = ch & 7;
            cp_glds16(w2t + row * 64 + ((sl ^ (row & 7)) << 3), &ws2[cb * 8]);
        }
#pragma unroll
        for (int it = 0; it < 4; ++it) { // ws1: 512 chunks
            int cb = it * 128 + gw * 64;
            int ch = cb + lane;
            int row = ch >> 3, sl = ch & 7;
            cp_glds16(w1t + row * 64 + ((sl ^ (row & 7)) << 3), &ws1[cb * 8]);
        }
#pragma unroll
        for (int it = 0; it < 4; ++it) { // msgA: 512 chunks, per-lane gathered source
            int cb = it * 128 + gw * 64;
            int ch = cb + lane;
            int e = ch >> 2, sl = ch & 3;
            int gs = sl ^ (e & 3);
            int c = colp[e0 + e];
            cp_glds16(xfeat + (long)c * 32 + gs * 8, &msgA[cb * 8]);
        }
    } else {
        // waves 0-1: fused sfeat + msgB (cols 32..63), all lanes active
        int e = t;
        int r = r0 + (e >> 4);
        int c = colp[e0 + e];
        int ci = idxp[r];
        float dx = pos[c * 3 + 0] - pos[ci * 3 + 0];
        float dy = pos[c * 3 + 1] - pos[ci * 3 + 1];
        float dz = pos[c * 3 + 2] - pos[ci * 3 + 2];
        float dr = refl[c] - refl[ci];

        float nrm = sqrtf(dx * dx + dy * dy + dz * dz);
        float inv = __builtin_amdgcn_rcpf(nrm + 1e-8f);
        float ux = dx * inv, uy = dy * inv, uz = dz * inv;
#pragma unroll
        for (int msk = 1; msk <= 8; msk <<= 1) {
            ux += __shfl_xor(ux, msk);
            uy += __shfl_xor(uy, msk);
            uz += __shfl_xor(uz, msk);
        }
        const float S3_16 = 0.57735026918962576f * (1.0f / 16.0f);
        const float sxk[8] = {1, -1, 1, 1, -1, -1, 1, -1};
        const float syk[8] = {1, 1, -1, 1, -1, 1, -1, -1};
        const float szk[8] = {1, 1, 1, -1, 1, -1, -1, -1};
        float sc0 = lkb[0], sc1 = lkb[1], sc2 = lkb[2];
#pragma unroll
        for (int j = 0; j < 8; ++j) {
            float nb = (sxk[j] * ux + syk[j] * uy + szk[j] * uz) * S3_16;
            sc0 += nb * lkw[j * 3 + 0];
            sc1 += nb * lkw[j * 3 + 1];
            sc2 += nb * lkw[j * 3 + 2];
        }
        float mm = (sc0 + sc1 + sc2) * (1.0f / 3.0f);
        float vv = ((sc0 - mm) * (sc0 - mm) + (sc1 - mm) * (sc1 - mm) +
                    (sc2 - mm) * (sc2 - mm)) * (1.0f / 3.0f);
        float rstd = rsqrtf(fmaxf(vv, 0.0f) + 1e-5f);

        u16 tmp[8];
        tmp[0] = f2b_hw(dx);
        tmp[1] = f2b_hw(dy);
        tmp[2] = f2b_hw(dz);
        tmp[3] = f2b_hw(dr);
        tmp[4] = f2b_hw((sc0 - mm) * rstd * lng[0] + lnb[0]);
        tmp[5] = f2b_hw((sc1 - mm) * rstd * lng[1] + lnb[1]);
        tmp[6] = f2b_hw((sc2 - mm) * rstd * lng[2] + lnb[2]);
        tmp[7] = 0;
        uint4 z = {0, 0, 0, 0};
        // global seg gs lives at slot gs ^ (e&3); tmp is gs=0, zeros gs=1..3
        *(uint4*)(&msgB[(e * 4 + (e & 3)) * 8]) = *(uint4*)tmp;
#pragma unroll
        for (int gs = 1; gs < 4; ++gs)
            *(uint4*)(&msgB[(e * 4 + (gs ^ (e & 3))) * 8]) = z;
    }
    __syncthreads();   // ONE barrier: DMA drained + msgB visible

    // ---------------- stage 1: msg @ w1 -> h (SWAPPED mfma, packed in-place writes)
    {
        f32x4 acc[2][4];
#pragma unroll
        for (int i = 0; i < 2; ++i)
#pragma unroll
            for (int j = 0; j < 4; ++j) acc[i][j] = (f32x4){0.f, 0.f, 0.f, 0.f};
#pragma unroll
        for (int half = 0; half < 2; ++half) {   // kk = half*32
            u16x8 af[2], bfr[4];
#pragma unroll
            for (int i = 0; i < 2; ++i) {
                int row = (mt0 + i) * 16 + l16;
                const u16* buf = half ? msgB : msgA;
                af[i] = *(const u16x8*)(&buf[(row * 4 + (quad ^ (row & 3))) * 8]);
            }
#pragma unroll
            for (int j = 0; j < 4; ++j) {
                int r = j * 16 + l16;
                int ch = half * 4 + quad;
                bfr[j] = *(const u16x8*)(&ws1[(r * 8 + (ch ^ (r & 7))) * 8]);
            }
#pragma unroll
            for (int i = 0; i < 2; ++i)
#pragma unroll
                for (int j = 0; j < 4; ++j)
                    acc[i][j] = mfma_bf16(bfr[j], af[i], acc[i][j]);   // SWAPPED: D[n][m]
        }
        mai_guard();
        // lane: m = (mt0+i)*16 + l16 (own row), n = j*16 + quad*4 + r -> b64 pack
#pragma unroll
        for (int j = 0; j < 4; ++j) {
            f32x4 bv = *(const f32x4*)(b1 + j * 16 + quad * 4);
            int n0 = j * 16 + quad * 4;
            int lc = (n0 >> 3) & 3;
            int off = n0 & 7;
            u16* buf = (j < 2) ? msgA : msgB;
#pragma unroll
            for (int i = 0; i < 2; ++i) {
                f32x4 c = acc[i][j];
                int mrow = (mt0 + i) * 16 + l16;
                float v0 = silu_f(fmaf(BNCF, c[0], bv[0] * BNCF));
                float v1 = silu_f(fmaf(BNCF, c[1], bv[1] * BNCF));
                float v2 = silu_f(fmaf(BNCF, c[2], bv[2] * BNCF));
                float v3 = silu_f(fmaf(BNCF, c[3], bv[3] * BNCF));
                u32 p2[2] = { f2b2(v0, v1), f2b2(v2, v3) };
                *(u64*)(&buf[(mrow * 4 + (lc ^ (mrow & 3))) * 8 + off]) = *(u64*)p2;
            }
        }
    }
    // NO barrier: MFMA2 A-rows are this wave's own; ws2 resident since start.

    // ---------------- stage 2: h @ w2 -> segment max (unchanged layout)
    {
        f32x4 acc[2][8];
#pragma unroll
        for (int i = 0; i < 2; ++i)
#pragma unroll
            for (int j = 0; j < 8; ++j) acc[i][j] = (f32x4){0.f, 0.f, 0.f, 0.f};
#pragma unroll
        for (int half = 0; half < 2; ++half) {   // kk = half*32
            u16x8 af[2], bfr[8];
#pragma unroll
            for (int i = 0; i < 2; ++i) {
                int row = (mt0 + i) * 16 + l16;
                const u16* buf = half ? msgB : msgA;
                af[i] = *(const u16x8*)(&buf[(row * 4 + (quad ^ (row & 3))) * 8]);
            }
#pragma unroll
            for (int j = 0; j < 8; ++j) {
                int r = j * 16 + l16;
                int ch = half * 4 + quad;
                bfr[j] = *(const u16x8*)(&ws2[(r * 8 + (ch ^ (r & 7))) * 8]);
            }
#pragma unroll
            for (int i = 0; i < 2; ++i)
#pragma unroll
                for (int j = 0; j < 8; ++j)
                    acc[i][j] = mfma_bf16(af[i], bfr[j], acc[i][j]);
        }
        mai_guard();
        // max_e silu(x_e) == max(silu(max x), silu(min x)) — silu quasiconvex.
#pragma unroll
        for (int i = 0; i < 2; ++i) {
            int rg = r0 + mt0 + i;
#pragma unroll
            for (int j = 0; j < 8; ++j) {
                f32x4 c = acc[i][j];
                int n = j * 16 + l16;
                float mx = fmaxf(fmaxf(c[0], c[1]), fmaxf(c[2], c[3]));
                float mn = fminf(fminf(c[0], c[1]), fminf(c[2], c[3]));
                mx = fmaxf(mx, __shfl_xor(mx, 16));
                mx = fmaxf(mx, __shfl_xor(mx, 32));
                mn = fminf(mn, __shfl_xor(mn, 16));
                mn = fminf(mn, __shfl_xor(mn, 32));
                if (quad == 0) {
                    float v = fmaxf(silu_f(fmaf(BNCF, mx, b2A[j])),
                                    silu_f(fmaf(BNCF, mn, b2A[j])));
                    agg[(long)rg * 128 + n] = v;
                    aggb[(long)rg * 128 + n] = f2b_hw(v);
                }
            }
        }
    }
}

// ---------------------------------------------------------------- MFMA GEMM (async staging + XOR swizzle)
// Compile-time K/Nn; XCD sibling swizzle (NXB=4, relative locality, R7: -11.6us).
template <int EPI, int OD, int NXB, int K, int Nn>
__global__ __launch_bounds__(256, 4) void k_mgemm(const u16* __restrict__ A,
                                               const u16* __restrict__ Bt,
                                               const float* __restrict__ bias,
                                               const float* __restrict__ dww,
                                               const float* __restrict__ dwb,
                                               const float* __restrict__ res,
                                               void* __restrict__ Ov) {
    __shared__ u16 As[128 * 64];
    __shared__ u16 Bs[128 * 64];
    int t = threadIdx.x;
    int wave = t >> 6, lane = t & 63;
    int quad = lane >> 4, l16 = lane & 15;
    int bx, by;
    if (NXB == 4) {
        int d = blockIdx.x;
        int q = d >> 5, r = d & 31;       // 32 blocks = 8 row-panels x 4 siblings
        by = q * 8 + (r & 7);
        bx = r >> 3;
    } else {
        bx = 0; by = blockIdx.x;
    }
    int R0 = by * 128, C0 = bx * 128;
    int wm = (wave & 1) * 64, wn = (wave >> 1) * 64;

    int srow = (lane >> 3);                 // 0..7 within 8-row group
    int sch  = lane & 7;                    // 16B chunk 0..7

    f32x4 acc[4][4];
#pragma unroll
    for (int i = 0; i < 4; ++i)
#pragma unroll
        for (int j = 0; j < 4; ++j) acc[i][j] = (f32x4){0.f, 0.f, 0.f, 0.f};

    for (int k0 = 0; k0 < K; k0 += 64) {
#pragma unroll
        for (int it = 0; it < 4; ++it) {
            int base = wave * 32 + it * 8;
            int row = base + srow;
            int gch = (sch ^ (row & 7)) << 3;   // swizzled source chunk
            cp_glds16(A  + (long)(R0 + row) * K + k0 + gch, &As[base * 64]);
            cp_glds16(Bt + (long)(C0 + row) * K + k0 + gch, &Bs[base * 64]);
        }
        __syncthreads();
#pragma unroll
        for (int kk = 0; kk < 64; kk += 32) {
            int kb = kk >> 3;                    // 0 or 4
            u16x8 af[4], bfr[4];
#pragma unroll
            for (int tm = 0; tm < 4; ++tm) {
                int r = wm + tm * 16 + l16;
                af[tm] = *(const u16x8*)(&As[r * 64 + (((kb + quad) ^ (r & 7)) << 3)]);
            }
#pragma unroll
            for (int tn = 0; tn < 4; ++tn) {
                int r = wn + tn * 16 + l16;
                bfr[tn] = *(const u16x8*)(&Bs[r * 64 + (((kb + quad) ^ (r & 7)) << 3)]);
            }
#pragma unroll
            for (int tm = 0; tm < 4; ++tm)
#pragma unroll
                for (int tn = 0; tn < 4; ++tn)
                    acc[tm][tn] = mfma_bf16(af[tm], bfr[tn], acc[tm][tn]);
        }
        __syncthreads();
    }

    // hoisted per-tn epilogue scalars (static indexing -> registers)
    float bnA[4], dnA[4], dbA[4];
#pragma unroll
    for (int tn = 0; tn < 4; ++tn) {
        int n = C0 + wn + tn * 16 + l16;
        bnA[tn] = bias[n] * BNCF;
        if (EPI == 0 || EPI == 1) { dnA[tn] = dww[n] * BNCF; dbA[tn] = dwb[n] * BNCF; }
        else { dnA[tn] = 0.0f; dbA[tn] = 0.0f; }
    }
    mai_guard();
#pragma unroll
    for (int tm = 0; tm < 4; ++tm) {
#pragma unroll
        for (int tn = 0; tn < 4; ++tn) {
            f32x4 c = acc[tm][tn];
            int n = C0 + wn + tn * 16 + l16;
#pragma unroll
            for (int r = 0; r < 4; ++r) {
                int m = R0 + wm + tm * 16 + quad * 4 + r;
                float v = c[r];
                if (EPI == 0) {
                    v = silu_f(fmaf(BNCF, v, bnA[tn]));
                    v = silu_f(fmaf(v, dnA[tn], dbA[tn]));
                } else if (EPI == 1) {
                    v = silu_f(fmaf(BNCF, v, bnA[tn]));
                    v = silu_f(BNCF * v);
                    v = silu_f(fmaf(v, dnA[tn], dbA[tn]));
                } else if (EPI == 2) {
                    v = silu_f(fmaf(BNCF, v, bnA[tn]));
                    v = BNCF * v;
                } else {
                    v = fmaf(BNCF, v, bnA[tn]);
                    v = silu_f(v + res[(long)m * 128 + n]);
                }
                if (OD == 0)
                    ((u16*)Ov)[(long)m * Nn + n] = f2b_hw(v);
                else
                    ((float*)Ov)[(long)m * Nn + n] = v;
            }
        }
    }
}

// ---------------------------------------------------------------- launcher
extern "C" void kernel_launch(void* const* d_in, const int* in_sizes, int n_in,
                              void* d_out, int out_size, void* d_ws, size_t ws_size,
                              hipStream_t stream) {
    const float* pos   = (const float*)d_in[0];
    const float* refl  = (const float*)d_in[1];
    const float* sfv   = (const float*)d_in[2];
    const int*   batch = (const int*)d_in[3];
    const int*   idxp  = (const int*)d_in[4];
    const int*   colp  = (const int*)d_in[5];
    const float* s_g  = (const float*)d_in[7];
    const float* s_b  = (const float*)d_in[8];
    const float* s_w1 = (const float*)d_in[9];
    const float* s_b1 = (const float*)d_in[10];
    const float* s_w2 = (const float*)d_in[11];
    const float* s_b2 = (const float*)d_in[12];
    const float* lkw  = (const float*)d_in[13];
    const float* lkb  = (const float*)d_in[14];
    const float* lng  = (const float*)d_in[15];
    const float* lnb  = (const float*)d_in[16];
    const float* l_w1 = (const float*)d_in[17];
    const float* l_b1 = (const float*)d_in[18];
    const float* l_w2 = (const float*)d_in[19];
    const float* l_b2 = (const float*)d_in[20];
    const float* expw = (const float*)d_in[21];
    const float* expb = (const float*)d_in[22];
    const float* dw1w = (const float*)d_in[23];
    const float* dw1b = (const float*)d_in[24];
    const float* pw1w = (const float*)d_in[25];
    const float* pw1b = (const float*)d_in[26];
    const float* dw2w = (const float*)d_in[27];
    const float* dw2b = (const float*)d_in[28];
    const float* pw2w = (const float*)d_in[29];
    const float* pw2b = (const float*)d_in[30];
    const float* prjw = (const float*)d_in[31];
    const float* prjb = (const float*)d_in[32];

    char* ws = (char*)d_ws;
    float* cent  = (float*)(ws + 0);                  // 64 B
    float* agg   = (float*)(ws + 393280);             // M*128*4 f32
    u16*   aggb  = (u16*)(ws + 17170496);             // M*128*2 bf16
    u16*   u1    = (u16*)(ws + 25559104);             // M*512*2
    u16*   u2    = (u16*)(ws + 59113536);             // M*512*2
    u16*   xf    = (u16*)(ws + 59113536);             // N*32*2 (aliases u2; dead before u2 written)
    u16*   expwt = (u16*)(ws + 92667968);             // 512*128*2
    u16*   pw1t  = (u16*)(ws + 92799040);             // 512*512*2
    u16*   pw2t  = (u16*)(ws + 93323328);             // 512*512*2
    u16*   prjt  = (u16*)(ws + 93847616);             // 128*512*2
    u16*   lw1t  = (u16*)(ws + 93978688);             // 64*64*2   = 8192
    u16*   lw2t  = (u16*)(ws + 93986880);             // 128*64*2  = 16384
    u16*   sw1t  = (u16*)(ws + 94003264);             // 64*128*2  = 16384
    u16*   sw2t  = (u16*)(ws + 94019648);             // 32*64*2   = 4096

    k_prep<<<248, 256, 0, stream>>>(expw, expwt, pw1w, pw1t, pw2w, pw2t, prjw, prjt,
                                    l_w1, lw1t, l_w2, lw2t, s_w1, sw1t, s_w2, sw2t,
                                    cent);

    k_centers<<<512, 256, 0, stream>>>(pos, sfv, batch, cent);
    k_stem<<<1024, 256, 0, stream>>>(pos, refl, sfv, batch, cent, s_g, s_b,
                                     sw1t, s_b1, sw2t, s_b2, xf);
    k_edge<<<4096, 256, 0, stream>>>(pos, refl, idxp, colp, xf,
                                     lkw, lkb, lng, lnb,
                                     lw1t, l_b1, lw2t, l_b2, agg, aggb);

    dim3 blk(256);
    k_mgemm<0, 0, 4, 128, 512><<<1024, blk, 0, stream>>>(aggb, expwt, expb, dw1w, dw1b,
                                                         nullptr, u1);
    k_mgemm<1, 0, 4, 512, 512><<<1024, blk, 0, stream>>>(u1, pw1t, pw1b, dw2w, dw2b,
                                                         nullptr, u2);
    k_mgemm<2, 0, 4, 512, 512><<<1024, blk, 0, stream>>>(u2, pw2t, pw2b, nullptr, nullptr,
                                                         nullptr, u1);
    k_mgemm<3, 1, 1, 512, 128><<<256, blk, 0, stream>>>(u1, prjt, prjb, nullptr, nullptr,
                                                        agg, d_out);
}

// Round 17
// 279.486 us; speedup vs baseline: 1.0240x; 1.0240x over previous
//
#include <hip/hip_runtime.h>

typedef unsigned short u16;
typedef unsigned int   u32;
typedef unsigned long long u64;
typedef __attribute__((ext_vector_type(8))) u16  u16x8;
typedef __attribute__((ext_vector_type(4))) float f32x4;

#define N_PTS   131072
#define M_PTS   32768
#define BNCF    0.9999950000374997f

__device__ __forceinline__ float b2f(u16 u) {
    u32 x = ((u32)u) << 16;
    float f;
    __builtin_memcpy(&f, &x, 4);
    return f;
}
// cold-path bit-trick (RNE)
__device__ __forceinline__ u16 f2b(float f) {
    u32 x;
    __builtin_memcpy(&x, &f, 4);
    u32 r = x + 0x7fffu + ((x >> 16) & 1u);
    return (u16)(r >> 16);
}
// hot-path: single v_cvt_pk_bf16_f32 (RNE on finite values — identical to bit-trick)
__device__ __forceinline__ u16 f2b_hw(float f) {
    u32 r;
    asm("v_cvt_pk_bf16_f32 %0, %1, %1" : "=v"(r) : "v"(f));
    return (u16)r;
}
// packed: lo16 = bf16(a), hi16 = bf16(b) — one instruction for two converts
__device__ __forceinline__ u32 f2b2(float a, float b) {
    u32 r;
    asm("v_cvt_pk_bf16_f32 %0, %1, %2" : "=v"(r) : "v"(a), "v"(b));
    return r;
}
// silu without IEEE division: 5 ops (mul,exp,add,rcp,mul) vs ~13 with div sequence
__device__ __forceinline__ float silu_f(float x) {
    return x * __builtin_amdgcn_rcpf(1.0f + __expf(-x));
}

__device__ __forceinline__ f32x4 mfma_bf16(u16x8 a, u16x8 b, f32x4 c) {
    asm volatile("v_mfma_f32_16x16x32_bf16 %0, %1, %2, %0"
                 : "+v"(c) : "v"(a), "v"(b));
    return c;
}
// Single MAI->VALU wait-state guard, issued ONCE before each epilogue.
// NOTE (R14 lesson): inline-asm MFMA is invisible to the compiler's hazard
// logic — launch_bounds must NEVER force spills.
__device__ __forceinline__ void mai_guard() {
    asm volatile("s_nop 7\n\ts_nop 7\n\ts_nop 3");
}

// async global->LDS, 16B per lane. LDS dest = wave-uniform base + lane*16.
__device__ __forceinline__ void cp_glds16(const u16* g, u16* l) {
    typedef const __attribute__((address_space(1))) u32* gp1_t;
    typedef __attribute__((address_space(3))) u32* lp3_t;
    __builtin_amdgcn_global_load_lds((gp1_t)(unsigned long long)g,
                                     (lp3_t)(unsigned long long)l, 16, 0, 0);
}

// ---------------------------------------------------------------- all weight transposes in ONE dispatch
__global__ __launch_bounds__(256) void k_prep(const float* __restrict__ expw, u16* __restrict__ expwt,
                                              const float* __restrict__ pw1w, u16* __restrict__ pw1t,
                                              const float* __restrict__ pw2w, u16* __restrict__ pw2t,
                                              const float* __restrict__ prjw, u16* __restrict__ prjt,
                                              const float* __restrict__ lw1,  u16* __restrict__ lw1t,
                                              const float* __restrict__ lw2,  u16* __restrict__ lw2t,
                                              const float* __restrict__ sw1,  u16* __restrict__ sw1t,
                                              const float* __restrict__ sw2,  u16* __restrict__ sw2t,
                                              float* __restrict__ cent) {
    __shared__ u16 tile[64][66];
    int bid = blockIdx.x;
    if (bid < 160) {
        const float* W; u16* O; int K, Nn, tk, tn_;
        if (bid < 16)              { W = expw; O = expwt; K = 128; Nn = 512; tk = bid >> 3; tn_ = bid & 7; }
        else if ((bid -= 16) < 64) { W = pw1w; O = pw1t;  K = 512; Nn = 512; tk = bid >> 3; tn_ = bid & 7; }
        else if ((bid -= 64) < 64) { W = pw2w; O = pw2t;  K = 512; Nn = 512; tk = bid >> 3; tn_ = bid & 7; }
        else { bid -= 64;            W = prjw; O = prjt;  K = 512; Nn = 128; tk = bid >> 1; tn_ = bid & 1; }
        int k0 = tk * 64, n0 = tn_ * 64;
        int c = threadIdx.x & 63, r0 = threadIdx.x >> 6;
#pragma unroll
        for (int rr = 0; rr < 16; ++rr) {
            int row = r0 * 16 + rr;
            tile[row][c] = f2b(W[(long)(k0 + row) * Nn + n0 + c]);
        }
        __syncthreads();
#pragma unroll
        for (int rr = 0; rr < 16; ++rr) {
            int row = r0 * 16 + rr;
            O[(long)(n0 + row) * K + k0 + c] = tile[c][row];
        }
        return;
    }
    int idx = (bid - 160) * 256 + threadIdx.x;
    if (bid == 247 && threadIdx.x < 16) cent[threadIdx.x] = 0.0f;
    const float* W; u16* O; int K, ksh, Nn;
    if (idx < 4096)                  { W = lw1; O = lw1t; K = 39; ksh = 6; Nn = 64;  }
    else if ((idx -= 4096) < 8192)   { W = lw2; O = lw2t; K = 64; ksh = 6; Nn = 128; }
    else if ((idx -= 8192) < 8192)   { W = sw1; O = sw1t; K = 97; ksh = 7; Nn = 64;  }
    else if ((idx -= 8192) < 2048)   { W = sw2; O = sw2t; K = 64; ksh = 6; Nn = 32;  }
    else return;
    int n = idx >> ksh, k = idx & ((1 << ksh) - 1);
    O[idx] = (k < K) ? f2b(W[(long)k * Nn + n]) : (u16)0;
}

// ---------------------------------------------------------------- centers
__global__ __launch_bounds__(256) void k_centers(const float* __restrict__ pos,
                                                 const float* __restrict__ sfv,
                                                 const int* __restrict__ batch,
                                                 float* __restrict__ acc) {
    __shared__ float ls[16];
    int t = threadIdx.x, lane = t & 63, wave = t >> 6;
    int i = blockIdx.x * 256 + t;
    int b = batch[blockIdx.x * 256];                 // block-uniform
    float inv = 1.0f / sfv[b];
    float x = pos[i * 3 + 0] * inv;
    float y = pos[i * 3 + 1] * inv;
    float z = pos[i * 3 + 2] * inv;
#pragma unroll
    for (int m = 1; m < 64; m <<= 1) {
        x += __shfl_xor(x, m);
        y += __shfl_xor(y, m);
        z += __shfl_xor(z, m);
    }
    if (lane == 0) { ls[wave * 4 + 0] = x; ls[wave * 4 + 1] = y; ls[wave * 4 + 2] = z; }
    __syncthreads();
    if (t < 3) {
        float s = ls[t] + ls[4 + t] + ls[8 + t] + ls[12 + t];
        atomicAdd(&acc[b * 4 + t], s);
    }
    if (t == 3) atomicAdd(&acc[b * 4 + 3], 256.0f);
}

// ---------------------------------------------------------------- stem (MFMA) — R16 state (control)
__global__ __launch_bounds__(256, 4) void k_stem(const float* __restrict__ pos,
                                              const float* __restrict__ refl,
                                              const float* __restrict__ sfv,
                                              const int* __restrict__ batch,
                                              const float* __restrict__ cacc,
                                              const float* __restrict__ g,
                                              const float* __restrict__ bb,
                                              const u16* __restrict__ w1t,   // [64][128] bf16 (zero pad k>=97)
                                              const float* __restrict__ b1,
                                              const u16* __restrict__ w2t,   // [32][64] bf16
                                              const float* __restrict__ b2,
                                              u16* __restrict__ xout) {
    __shared__ u16 xs[128][136];
    const float FLO[8] = {
        1.0f, 0.31622776601683794f, 0.1f, 0.031622776601683791f,
        0.01f, 0.0031622776601683794f, 0.001f, 0.00031622776601683794f};
    const float FHI[8] = {
        0.0001f, 3.1622776601683795e-05f, 1e-05f, 3.1622776601683796e-06f,
        1e-06f, 3.1622776601683797e-07f, 1e-07f, 3.1622776601683792e-08f};
    int t = threadIdx.x;
    int wave = t >> 6, lane = t & 63;
    int quad = lane >> 4, l16 = lane & 15;
    int mt0 = wave * 2;

    {
        int p = t >> 1, half = t & 1;
        int i = blockIdx.x * 128 + p;
        int b = batch[i];
        float s = 1.0f / sfv[b];
        float cnt = fmaxf(cacc[b * 4 + 3], 1.0f);
        float npv[3];
#pragma unroll
        for (int d = 0; d < 3; ++d)
            npv[d] = pos[i * 3 + d] * s - cacc[b * 4 + d] / cnt;

        float fq[8];
#pragma unroll
        for (int f = 0; f < 8; ++f) fq[f] = half ? FHI[f] : FLO[f];

        float sv[3][8], cv[3][8];
        float sum = 0.0f, sq = 0.0f;
#pragma unroll
        for (int d = 0; d < 3; ++d) {
#pragma unroll
            for (int f = 0; f < 8; ++f) {
                float a = npv[d] * fq[f];
                float s_, c_;
                __sincosf(a, &s_, &c_);
                sv[d][f] = s_;
                cv[d][f] = c_;
                sum += s_ + c_;
                sq += s_ * s_ + c_ * c_;
            }
        }
        float rf = refl[i];
        if (half == 0) { sum += rf; sq += rf * rf; }
        sum += __shfl_xor(sum, 1);
        sq  += __shfl_xor(sq, 1);

        float m = sum * (1.0f / 97.0f);
        float var = sq * (1.0f / 97.0f) - m * m;
        float rstd = rsqrtf(fmaxf(var, 0.0f) + 1e-5f);

#pragma unroll
        for (int d = 0; d < 3; ++d) {
            int c0 = d * 32 + half * 8;          // sin block
            {
                f32x4 g0  = *(const f32x4*)(g + c0);
                f32x4 g1  = *(const f32x4*)(g + c0 + 4);
                f32x4 bb0 = *(const f32x4*)(bb + c0);
                f32x4 bb1 = *(const f32x4*)(bb + c0 + 4);
                u16 tmp[8];
#pragma unroll
                for (int f = 0; f < 4; ++f) {
                    tmp[f]     = f2b_hw((sv[d][f]     - m) * rstd * g0[f] + bb0[f]);
                    tmp[4 + f] = f2b_hw((sv[d][4 + f] - m) * rstd * g1[f] + bb1[f]);
                }
                *(uint4*)(&xs[p][c0]) = *(uint4*)tmp;
            }
            int c1 = d * 32 + 16 + half * 8;     // cos block
            {
                f32x4 g0  = *(const f32x4*)(g + c1);
                f32x4 g1  = *(const f32x4*)(g + c1 + 4);
                f32x4 bb0 = *(const f32x4*)(bb + c1);
                f32x4 bb1 = *(const f32x4*)(bb + c1 + 4);
                u16 tmp[8];
#pragma unroll
                for (int f = 0; f < 4; ++f) {
                    tmp[f]     = f2b_hw((cv[d][f]     - m) * rstd * g0[f] + bb0[f]);
                    tmp[4 + f] = f2b_hw((cv[d][4 + f] - m) * rstd * g1[f] + bb1[f]);
                }
                *(uint4*)(&xs[p][c1]) = *(uint4*)tmp;
            }
        }
        if (half == 0) {
            float v = rf;
            u16 tmp[8];
            tmp[0] = f2b_hw((v - m) * rstd * g[96] + bb[96]);
#pragma unroll
            for (int f = 1; f < 8; ++f) tmp[f] = 0;
            *(uint4*)(&xs[p][96]) = *(uint4*)tmp;    // cols 96..103
        } else {
            uint4 z = {0, 0, 0, 0};
            *(uint4*)(&xs[p][104]) = z;              // cols 104..127
            *(uint4*)(&xs[p][112]) = z;
            *(uint4*)(&xs[p][120]) = z;
        }
    }
    // NO barrier: per-wave row ownership (same-wave DS in-order).

    {
        f32x4 acc[2][4];
#pragma unroll
        for (int i = 0; i < 2; ++i)
#pragma unroll
            for (int j = 0; j < 4; ++j) acc[i][j] = (f32x4){0.f, 0.f, 0.f, 0.f};
#pragma unroll
        for (int kk = 0; kk < 128; kk += 32) {
            u16x8 af[2], bfr[4];
#pragma unroll
            for (int i = 0; i < 2; ++i)
                af[i] = *(const u16x8*)(&xs[(mt0 + i) * 16 + l16][kk + quad * 8]);
#pragma unroll
            for (int j = 0; j < 4; ++j)
                bfr[j] = *(const u16x8*)(w1t + (j * 16 + l16) * 128 + kk + quad * 8);
#pragma unroll
            for (int i = 0; i < 2; ++i)
#pragma unroll
                for (int j = 0; j < 4; ++j)
                    acc[i][j] = mfma_bf16(bfr[j], af[i], acc[i][j]);   // SWAPPED: D[n][m]
        }
        mai_guard();
#pragma unroll
        for (int j = 0; j < 4; ++j) {
            f32x4 bv = *(const f32x4*)(b1 + j * 16 + quad * 4);
#pragma unroll
            for (int i = 0; i < 2; ++i) {
                f32x4 c = acc[i][j];
                int mrow = (mt0 + i) * 16 + l16;
                float v0 = silu_f(fmaf(BNCF, c[0], bv[0] * BNCF));
                float v1 = silu_f(fmaf(BNCF, c[1], bv[1] * BNCF));
                float v2 = silu_f(fmaf(BNCF, c[2], bv[2] * BNCF));
                float v3 = silu_f(fmaf(BNCF, c[3], bv[3] * BNCF));
                u32 p2[2] = { f2b2(v0, v1), f2b2(v2, v3) };
                *(u64*)(&xs[mrow][j * 16 + quad * 4]) = *(u64*)p2;
            }
        }
    }
    // NO barrier: stage-2 reads only this wave's own rows.

    {
        f32x4 acc[2][2];
#pragma unroll
        for (int i = 0; i < 2; ++i)
#pragma unroll
            for (int j = 0; j < 2; ++j) acc[i][j] = (f32x4){0.f, 0.f, 0.f, 0.f};
#pragma unroll
        for (int kk = 0; kk < 64; kk += 32) {
            u16x8 af[2], bfr[2];
#pragma unroll
            for (int i = 0; i < 2; ++i)
                af[i] = *(const u16x8*)(&xs[(mt0 + i) * 16 + l16][kk + quad * 8]);
#pragma unroll
            for (int j = 0; j < 2; ++j)
                bfr[j] = *(const u16x8*)(w2t + (j * 16 + l16) * 64 + kk + quad * 8);
#pragma unroll
            for (int i = 0; i < 2; ++i)
#pragma unroll
                for (int j = 0; j < 2; ++j)
                    acc[i][j] = mfma_bf16(bfr[j], af[i], acc[i][j]);   // SWAPPED: D[n][m]
        }
        mai_guard();
#pragma unroll
        for (int j = 0; j < 2; ++j) {
            f32x4 bv = *(const f32x4*)(b2 + j * 16 + quad * 4);
#pragma unroll
            for (int i = 0; i < 2; ++i) {
                f32x4 c = acc[i][j];
                int m = (mt0 + i) * 16 + l16;
                long ig = (long)blockIdx.x * 128 + m;
                float v0 = silu_f(fmaf(BNCF, c[0], bv[0] * BNCF));
                float v1 = silu_f(fmaf(BNCF, c[1], bv[1] * BNCF));
                float v2 = silu_f(fmaf(BNCF, c[2], bv[2] * BNCF));
                float v3 = silu_f(fmaf(BNCF, c[3], bv[3] * BNCF));
                u32 p2[2] = { f2b2(v0, v1), f2b2(v2, v3) };
                *(u64*)(xout + ig * 32 + j * 16 + quad * 4) = *(u64*)p2;
            }
        }
    }
}

// ---------------------------------------------------------------- edge MLP + segment max (MFMA) — R16 state (control)
__global__ __launch_bounds__(256, 4) void k_edge(const float* __restrict__ pos,
                                              const float* __restrict__ refl,
                                              const int* __restrict__ idxp,
                                              const int* __restrict__ colp,
                                              const u16* __restrict__ xfeat,
                                              const float* __restrict__ lkw,
                                              const float* __restrict__ lkb,
                                              const float* __restrict__ lng,
                                              const float* __restrict__ lnb,
                                              const u16* __restrict__ w1t,
                                              const float* __restrict__ b1,
                                              const u16* __restrict__ w2t,
                                              const float* __restrict__ b2,
                                              float* __restrict__ agg,
                                              u16* __restrict__ aggb) {
    __shared__ u16 msgA[128 * 32];   // msg cols 0..31 -> h cols 0..31
    __shared__ u16 msgB[128 * 32];   // msg cols 32..63 -> h cols 32..63
    __shared__ u16 ws1[64 * 64];     // w1, slot = gch ^ (row&7)
    __shared__ u16 ws2[128 * 64];    // w2, slot = gch ^ (row&7)
    int t = threadIdx.x;
    int r0 = blockIdx.x * 8;
    long e0 = (long)r0 * 16;
    int wave = t >> 6, lane = t & 63;
    int quad = lane >> 4, l16 = lane & 15;
    int mt0 = wave * 2;

    float b2A[8];
#pragma unroll
    for (int j = 0; j < 8; ++j) b2A[j] = b2[j * 16 + l16] * BNCF;

    if (t >= 128) {
        int gw = (t >> 6) - 2;           // 0/1
#pragma unroll
        for (int it = 0; it < 8; ++it) { // ws2: 1024 chunks
            int cb = it * 128 + gw * 64;
            int ch = cb + lane;
            int row = ch >> 3, sl = ch & 7;
            cp_glds16(w2t + row * 64 + ((sl ^ (row & 7)) << 3), &ws2[cb * 8]);
        }
#pragma unroll
        for (int it = 0; it < 4; ++it) { // ws1: 512 chunks
            int cb = it * 128 + gw * 64;
            int ch = cb + lane;
            int row = ch >> 3, sl = ch & 7;
            cp_glds16(w1t + row * 64 + ((sl ^ (row & 7)) << 3), &ws1[cb * 8]);
        }
#pragma unroll
        for (int it = 0; it < 4; ++it) { // msgA: 512 chunks, per-lane gathered source
            int cb = it * 128 + gw * 64;
            int ch = cb + lane;
            int e = ch >> 2, sl = ch & 3;
            int gs = sl ^ (e & 3);
            int c = colp[e0 + e];
            cp_glds16(xfeat + (long)c * 32 + gs * 8, &msgA[cb * 8]);
        }
    } else {
        int e = t;
        int r = r0 + (e >> 4);
        int c = colp[e0 + e];
        int ci = idxp[r];
        float dx = pos[c * 3 + 0] - pos[ci * 3 + 0];
        float dy = pos[c * 3 + 1] - pos[ci * 3 + 1];
        float dz = pos[c * 3 + 2] - pos[ci * 3 + 2];
        float dr = refl[c] - refl[ci];

        float nrm = sqrtf(dx * dx + dy * dy + dz * dz);
        float inv = __builtin_amdgcn_rcpf(nrm + 1e-8f);
        float ux = dx * inv, uy = dy * inv, uz = dz * inv;
#pragma unroll
        for (int msk = 1; msk <= 8; msk <<= 1) {
            ux += __shfl_xor(ux, msk);
            uy += __shfl_xor(uy, msk);
            uz += __shfl_xor(uz, msk);
        }
        const float S3_16 = 0.57735026918962576f * (1.0f / 16.0f);
        const float sxk[8] = {1, -1, 1, 1, -1, -1, 1, -1};
        const float syk[8] = {1, 1, -1, 1, -1, 1, -1, -1};
        const float szk[8] = {1, 1, 1, -1, 1, -1, -1, -1};
        float sc0 = lkb[0], sc1 = lkb[1], sc2 = lkb[2];
#pragma unroll
        for (int j = 0; j < 8; ++j) {
            float nb = (sxk[j] * ux + syk[j] * uy + szk[j] * uz) * S3_16;
            sc0 += nb * lkw[j * 3 + 0];
            sc1 += nb * lkw[j * 3 + 1];
            sc2 += nb * lkw[j * 3 + 2];
        }
        float mm = (sc0 + sc1 + sc2) * (1.0f / 3.0f);
        float vv = ((sc0 - mm) * (sc0 - mm) + (sc1 - mm) * (sc1 - mm) +
                    (sc2 - mm) * (sc2 - mm)) * (1.0f / 3.0f);
        float rstd = rsqrtf(fmaxf(vv, 0.0f) + 1e-5f);

        u16 tmp[8];
        tmp[0] = f2b_hw(dx);
        tmp[1] = f2b_hw(dy);
        tmp[2] = f2b_hw(dz);
        tmp[3] = f2b_hw(dr);
        tmp[4] = f2b_hw((sc0 - mm) * rstd * lng[0] + lnb[0]);
        tmp[5] = f2b_hw((sc1 - mm) * rstd * lng[1] + lnb[1]);
        tmp[6] = f2b_hw((sc2 - mm) * rstd * lng[2] + lnb[2]);
        tmp[7] = 0;
        uint4 z = {0, 0, 0, 0};
        *(uint4*)(&msgB[(e * 4 + (e & 3)) * 8]) = *(uint4*)tmp;
#pragma unroll
        for (int gs = 1; gs < 4; ++gs)
            *(uint4*)(&msgB[(e * 4 + (gs ^ (e & 3))) * 8]) = z;
    }
    __syncthreads();   // ONE barrier: DMA drained + msgB visible

    // ---------------- stage 1: msg @ w1 -> h (SWAPPED mfma, packed in-place writes)
    {
        f32x4 acc[2][4];
#pragma unroll
        for (int i = 0; i < 2; ++i)
#pragma unroll
            for (int j = 0; j < 4; ++j) acc[i][j] = (f32x4){0.f, 0.f, 0.f, 0.f};
#pragma unroll
        for (int half = 0; half < 2; ++half) {   // kk = half*32
            u16x8 af[2], bfr[4];
#pragma unroll
            for (int i = 0; i < 2; ++i) {
                int row = (mt0 + i) * 16 + l16;
                const u16* buf = half ? msgB : msgA;
                af[i] = *(const u16x8*)(&buf[(row * 4 + (quad ^ (row & 3))) * 8]);
            }
#pragma unroll
            for (int j = 0; j < 4; ++j) {
                int r = j * 16 + l16;
                int ch = half * 4 + quad;
                bfr[j] = *(const u16x8*)(&ws1[(r * 8 + (ch ^ (r & 7))) * 8]);
            }
#pragma unroll
            for (int i = 0; i < 2; ++i)
#pragma unroll
                for (int j = 0; j < 4; ++j)
                    acc[i][j] = mfma_bf16(bfr[j], af[i], acc[i][j]);   // SWAPPED: D[n][m]
        }
        mai_guard();
#pragma unroll
        for (int j = 0; j < 4; ++j) {
            f32x4 bv = *(const f32x4*)(b1 + j * 16 + quad * 4);
            int n0 = j * 16 + quad * 4;
            int lc = (n0 >> 3) & 3;
            int off = n0 & 7;
            u16* buf = (j < 2) ? msgA : msgB;
#pragma unroll
            for (int i = 0; i < 2; ++i) {
                f32x4 c = acc[i][j];
                int mrow = (mt0 + i) * 16 + l16;
                float v0 = silu_f(fmaf(BNCF, c[0], bv[0] * BNCF));
                float v1 = silu_f(fmaf(BNCF, c[1], bv[1] * BNCF));
                float v2 = silu_f(fmaf(BNCF, c[2], bv[2] * BNCF));
                float v3 = silu_f(fmaf(BNCF, c[3], bv[3] * BNCF));
                u32 p2[2] = { f2b2(v0, v1), f2b2(v2, v3) };
                *(u64*)(&buf[(mrow * 4 + (lc ^ (mrow & 3))) * 8 + off]) = *(u64*)p2;
            }
        }
    }
    // NO barrier: MFMA2 A-rows are this wave's own; ws2 resident since start.

    // ---------------- stage 2: h @ w2 -> segment max
    {
        f32x4 acc[2][8];
#pragma unroll
        for (int i = 0; i < 2; ++i)
#pragma unroll
            for (int j = 0; j < 8; ++j) acc[i][j] = (f32x4){0.f, 0.f, 0.f, 0.f};
#pragma unroll
        for (int half = 0; half < 2; ++half) {   // kk = half*32
            u16x8 af[2], bfr[8];
#pragma unroll
            for (int i = 0; i < 2; ++i) {
                int row = (mt0 + i) * 16 + l16;
                const u16* buf = half ? msgB : msgA;
                af[i] = *(const u16x8*)(&buf[(row * 4 + (quad ^ (row & 3))) * 8]);
            }
#pragma unroll
            for (int j = 0; j < 8; ++j) {
                int r = j * 16 + l16;
                int ch = half * 4 + quad;
                bfr[j] = *(const u16x8*)(&ws2[(r * 8 + (ch ^ (r & 7))) * 8]);
            }
#pragma unroll
            for (int i = 0; i < 2; ++i)
#pragma unroll
                for (int j = 0; j < 8; ++j)
                    acc[i][j] = mfma_bf16(af[i], bfr[j], acc[i][j]);
        }
        mai_guard();
        // max_e silu(x_e) == max(silu(max x), silu(min x)) — silu quasiconvex.
#pragma unroll
        for (int i = 0; i < 2; ++i) {
            int rg = r0 + mt0 + i;
#pragma unroll
            for (int j = 0; j < 8; ++j) {
                f32x4 c = acc[i][j];
                int n = j * 16 + l16;
                float mx = fmaxf(fmaxf(c[0], c[1]), fmaxf(c[2], c[3]));
                float mn = fminf(fminf(c[0], c[1]), fminf(c[2], c[3]));
                mx = fmaxf(mx, __shfl_xor(mx, 16));
                mx = fmaxf(mx, __shfl_xor(mx, 32));
                mn = fminf(mn, __shfl_xor(mn, 16));
                mn = fminf(mn, __shfl_xor(mn, 32));
                if (quad == 0) {
                    float v = fmaxf(silu_f(fmaf(BNCF, mx, b2A[j])),
                                    silu_f(fmaf(BNCF, mn, b2A[j])));
                    agg[(long)rg * 128 + n] = v;
                    aggb[(long)rg * 128 + n] = f2b_hw(v);
                }
            }
        }
    }
}

// ---------------------------------------------------------------- MFMA GEMM — NEW: BK=32 double-buffer prefetch
// Old: stage(k) -> barrier (vmcnt(0) drain EXPOSES full L2 latency) -> compute -> barrier.
// New: per step: barrier -> issue stage(next, buf^1) -> compute(cur). The next
// iteration's barrier drains a prefetch that had a full compute phase to land.
// LDS 2x(128x32)x2 = 32KB (same 4 blocks/CU — avoids m99/m132 dbuf-occupancy trap).
// Same FP accumulation order (K-slices 0,32,64,...). Plain __syncthreads only.
// Swizzle g(row)=(row^(row>>2))&3 over 4 chunks/row: 16 lanes -> 8 banks (2-way, free).
template <int EPI, int OD, int NXB, int K, int Nn>
__global__ __launch_bounds__(256, 4) void k_mgemm(const u16* __restrict__ A,
                                               const u16* __restrict__ Bt,
                                               const float* __restrict__ bias,
                                               const float* __restrict__ dww,
                                               const float* __restrict__ dwb,
                                               const float* __restrict__ res,
                                               void* __restrict__ Ov) {
    __shared__ u16 As[2][128 * 32];
    __shared__ u16 Bs[2][128 * 32];
    int t = threadIdx.x;
    int wave = t >> 6, lane = t & 63;
    int quad = lane >> 4, l16 = lane & 15;
    int bx, by;
    if (NXB == 4) {
        int d = blockIdx.x;
        int q = d >> 5, r = d & 31;       // 32 blocks = 8 row-panels x 4 siblings
        by = q * 8 + (r & 7);
        bx = r >> 3;
    } else {
        bx = 0; by = blockIdx.x;
    }
    int R0 = by * 128, C0 = bx * 128;
    int wm = (wave & 1) * 64, wn = (wave >> 1) * 64;

    // staging geometry: per wave per matrix, 2 issues of 16 rows x 4 chunks
    int srow = lane >> 2;                   // 0..15 row offset within 16-row group
    int sch  = lane & 3;                    // dest chunk 0..3

    f32x4 acc[4][4];
#pragma unroll
    for (int i = 0; i < 4; ++i)
#pragma unroll
        for (int j = 0; j < 4; ++j) acc[i][j] = (f32x4){0.f, 0.f, 0.f, 0.f};

    // prologue: stage k0=0 into buf 0
#pragma unroll
    for (int it = 0; it < 2; ++it) {
        int rb = wave * 32 + it * 16;
        int row = rb + srow;
        int gs = (sch ^ ((row ^ (row >> 2)) & 3)) << 3;
        cp_glds16(A  + (long)(R0 + row) * K + gs, &As[0][rb * 32]);
        cp_glds16(Bt + (long)(C0 + row) * K + gs, &Bs[0][rb * 32]);
    }

    constexpr int NSTEP = K / 32;
#pragma unroll
    for (int s = 0; s < NSTEP; ++s) {
        const int cur = s & 1;
        __syncthreads();                    // drains buf[cur]'s stage (overlapped w/ prev compute)
        if (s + 1 < NSTEP) {                // issue prefetch AFTER the barrier
            int k0n = (s + 1) * 32;
#pragma unroll
            for (int it = 0; it < 2; ++it) {
                int rb = wave * 32 + it * 16;
                int row = rb + srow;
                int gs = (sch ^ ((row ^ (row >> 2)) & 3)) << 3;
                cp_glds16(A  + (long)(R0 + row) * K + k0n + gs, &As[cur ^ 1][rb * 32]);
                cp_glds16(Bt + (long)(C0 + row) * K + k0n + gs, &Bs[cur ^ 1][rb * 32]);
            }
        }
        // compute buf[cur] while prefetch is in flight
        u16x8 af[4], bfr[4];
#pragma unroll
        for (int tm = 0; tm < 4; ++tm) {
            int r = wm + tm * 16 + l16;
            int slot = quad ^ ((r ^ (r >> 2)) & 3);
            af[tm] = *(const u16x8*)(&As[cur][(r * 4 + slot) * 8]);
        }
#pragma unroll
        for (int tn = 0; tn < 4; ++tn) {
            int r = wn + tn * 16 + l16;
            int slot = quad ^ ((r ^ (r >> 2)) & 3);
            bfr[tn] = *(const u16x8*)(&Bs[cur][(r * 4 + slot) * 8]);
        }
#pragma unroll
        for (int tm = 0; tm < 4; ++tm)
#pragma unroll
            for (int tn = 0; tn < 4; ++tn)
                acc[tm][tn] = mfma_bf16(af[tm], bfr[tn], acc[tm][tn]);
    }

    // hoisted per-tn epilogue scalars (static indexing -> registers)
    float bnA[4], dnA[4], dbA[4];
#pragma unroll
    for (int tn = 0; tn < 4; ++tn) {
        int n = C0 + wn + tn * 16 + l16;
        bnA[tn] = bias[n] * BNCF;
        if (EPI == 0 || EPI == 1) { dnA[tn] = dww[n] * BNCF; dbA[tn] = dwb[n] * BNCF; }
        else { dnA[tn] = 0.0f; dbA[tn] = 0.0f; }
    }
    mai_guard();
#pragma unroll
    for (int tm = 0; tm < 4; ++tm) {
#pragma unroll
        for (int tn = 0; tn < 4; ++tn) {
            f32x4 c = acc[tm][tn];
            int n = C0 + wn + tn * 16 + l16;
#pragma unroll
            for (int r = 0; r < 4; ++r) {
                int m = R0 + wm + tm * 16 + quad * 4 + r;
                float v = c[r];
                if (EPI == 0) {
                    v = silu_f(fmaf(BNCF, v, bnA[tn]));
                    v = silu_f(fmaf(v, dnA[tn], dbA[tn]));
                } else if (EPI == 1) {
                    v = silu_f(fmaf(BNCF, v, bnA[tn]));
                    v = silu_f(BNCF * v);
                    v = silu_f(fmaf(v, dnA[tn], dbA[tn]));
                } else if (EPI == 2) {
                    v = silu_f(fmaf(BNCF, v, bnA[tn]));
                    v = BNCF * v;
                } else {
                    v = fmaf(BNCF, v, bnA[tn]);
                    v = silu_f(v + res[(long)m * 128 + n]);
                }
                if (OD == 0)
                    ((u16*)Ov)[(long)m * Nn + n] = f2b_hw(v);
                else
                    ((float*)Ov)[(long)m * Nn + n] = v;
            }
        }
    }
}

// ---------------------------------------------------------------- launcher
extern "C" void kernel_launch(void* const* d_in, const int* in_sizes, int n_in,
                              void* d_out, int out_size, void* d_ws, size_t ws_size,
                              hipStream_t stream) {
    const float* pos   = (const float*)d_in[0];
    const float* refl  = (const float*)d_in[1];
    const float* sfv   = (const float*)d_in[2];
    const int*   batch = (const int*)d_in[3];
    const int*   idxp  = (const int*)d_in[4];
    const int*   colp  = (const int*)d_in[5];
    const float* s_g  = (const float*)d_in[7];
    const float* s_b  = (const float*)d_in[8];
    const float* s_w1 = (const float*)d_in[9];
    const float* s_b1 = (const float*)d_in[10];
    const float* s_w2 = (const float*)d_in[11];
    const float* s_b2 = (const float*)d_in[12];
    const float* lkw  = (const float*)d_in[13];
    const float* lkb  = (const float*)d_in[14];
    const float* lng  = (const float*)d_in[15];
    const float* lnb  = (const float*)d_in[16];
    const float* l_w1 = (const float*)d_in[17];
    const float* l_b1 = (const float*)d_in[18];
    const float* l_w2 = (const float*)d_in[19];
    const float* l_b2 = (const float*)d_in[20];
    const float* expw = (const float*)d_in[21];
    const float* expb = (const float*)d_in[22];
    const float* dw1w = (const float*)d_in[23];
    const float* dw1b = (const float*)d_in[24];
    const float* pw1w = (const float*)d_in[25];
    const float* pw1b = (const float*)d_in[26];
    const float* dw2w = (const float*)d_in[27];
    const float* dw2b = (const float*)d_in[28];
    const float* pw2w = (const float*)d_in[29];
    const float* pw2b = (const float*)d_in[30];
    const float* prjw = (const float*)d_in[31];
    const float* prjb = (const float*)d_in[32];

    char* ws = (char*)d_ws;
    float* cent  = (float*)(ws + 0);                  // 64 B
    float* agg   = (float*)(ws + 393280);             // M*128*4 f32
    u16*   aggb  = (u16*)(ws + 17170496);             // M*128*2 bf16
    u16*   u1    = (u16*)(ws + 25559104);             // M*512*2
    u16*   u2    = (u16*)(ws + 59113536);             // M*512*2
    u16*   xf    = (u16*)(ws + 59113536);             // N*32*2 (aliases u2; dead before u2 written)
    u16*   expwt = (u16*)(ws + 92667968);             // 512*128*2
    u16*   pw1t  = (u16*)(ws + 92799040);             // 512*512*2
    u16*   pw2t  = (u16*)(ws + 93323328);             // 512*512*2
    u16*   prjt  = (u16*)(ws + 93847616);             // 128*512*2
    u16*   lw1t  = (u16*)(ws + 93978688);             // 64*64*2   = 8192
    u16*   lw2t  = (u16*)(ws + 93986880);             // 128*64*2  = 16384
    u16*   sw1t  = (u16*)(ws + 94003264);             // 64*128*2  = 16384
    u16*   sw2t  = (u16*)(ws + 94019648);             // 32*64*2   = 4096

    k_prep<<<248, 256, 0, stream>>>(expw, expwt, pw1w, pw1t, pw2w, pw2t, prjw, prjt,
                                    l_w1, lw1t, l_w2, lw2t, s_w1, sw1t, s_w2, sw2t,
                                    cent);

    k_centers<<<512, 256, 0, stream>>>(pos, sfv, batch, cent);
    k_stem<<<1024, 256, 0, stream>>>(pos, refl, sfv, batch, cent, s_g, s_b,
                                     sw1t, s_b1, sw2t, s_b2, xf);
    k_edge<<<4096, 256, 0, stream>>>(pos, refl, idxp, colp, xf,
                                     lkw, lkb, lng, lnb,
                                     lw1t, l_b1, lw2t, l_b2, agg, aggb);

    dim3 blk(256);
    k_mgemm<0, 0, 4, 128, 512><<<1024, blk, 0, stream>>>(aggb, expwt, expb, dw1w, dw1b,
                                                         nullptr, u1);
    k_mgemm<1, 0, 4, 512, 512><<<1024, blk, 0, stream>>>(u1, pw1t, pw1b, dw2w, dw2b,
                                                         nullptr, u2);
    k_mgemm<2, 0, 4, 512, 512><<<1024, blk, 0, stream>>>(u2, pw2t, pw2b, nullptr, nullptr,
                                                         nullptr, u1);
    k_mgemm<3, 1, 1, 512, 128><<<256, blk, 0, stream>>>(u1, prjt, prjb, nullptr, nullptr,
                                                        agg, d_out);
}